// Round 3
// baseline (104.385 us; speedup 1.0000x reference)
//
#include <hip/hip_runtime.h>
#include <math.h>
#include <string.h>

#define N 12288
#define TILE 96           // j-points per block (one LDS tile)
#define ACCS 8            // i-points per thread
#define IB (256 * ACCS)   // 2048 i-points per block
#define NBX (N / IB)      // 6
#define NBY (N / TILE)    // 128  -> grid 768 = exactly 3 blocks/CU

typedef unsigned long long ull;
typedef float v2f __attribute__((ext_vector_type(2)));

struct CMat { float c[6][6]; };

// ---------------------------------------------------------------------------
// Kernel A: brute-force masked NN. Block (bx,by) owns i in [bx*2048, +2048)
// (8 per thread, packed 2-wide for v_pk_fma_f32) and j in [by*96, +96) in LDS.
// Key is d2' = sqj_masked - 2*dot (sqi added back in the reducer).
// Writes (monotone-key<<32 | j) to private slot packed[by*N + i] — no atomics.
// ---------------------------------------------------------------------------
__device__ __forceinline__ void upd(float dv, int k, bool excl,
                                    float& bd, int& bk)
{
    if (!excl && dv < bd) { bd = dv; bk = k; }
}

template<bool CAREFUL>
__device__ __forceinline__ void nn_inner(
    const float4* __restrict__ tile, int jbase, int ibase_t,
    const v2f* wx, const v2f* wy, const v2f* wz,
    float* bd, int* bk)
{
    #pragma unroll 8
    for (int k = 0; k < TILE; ++k) {
        const float4 b = tile[k];
        const int jj = jbase + k;      // wave-uniform
        #pragma unroll
        for (int g = 0; g < ACCS / 2; ++g) {
            v2f dot = wx[g] * b.x;
            dot = dot + wy[g] * b.y;   // contracts to v_pk_fma_f32
            dot = dot + wz[g] * b.z;
            const v2f d = b.w - 2.0f * dot;
            const int a0 = 2 * g, a1 = 2 * g + 1;
            bool e0 = false, e1 = false;
            if (CAREFUL) {
                e0 = (jj == ibase_t + a0 * 256);
                e1 = (jj == ibase_t + a1 * 256);
            }
            upd(d.x, k, e0, bd[a0], bk[a0]);
            upd(d.y, k, e1, bd[a1], bk[a1]);
        }
    }
}

__global__ __launch_bounds__(256) void nn_kernel(
    const float* __restrict__ new_xyz,
    const float* __restrict__ gt_sdf,
    ull* __restrict__ packed)
{
    const int tid = threadIdx.x;
    const int bx = blockIdx.x;
    const int by = blockIdx.y;

    const int ibase = bx * IB;
    const int ibase_t = ibase + tid;   // i of acc a is ibase_t + a*256

    v2f wx[ACCS / 2], wy[ACCS / 2], wz[ACCS / 2];
    #pragma unroll
    for (int g = 0; g < ACCS / 2; ++g) {
        const int ia = ibase_t + (2 * g) * 256;
        const int ib2 = ibase_t + (2 * g + 1) * 256;
        wx[g] = (v2f){ new_xyz[3 * ia + 0], new_xyz[3 * ib2 + 0] };
        wy[g] = (v2f){ new_xyz[3 * ia + 1], new_xyz[3 * ib2 + 1] };
        wz[g] = (v2f){ new_xyz[3 * ia + 2], new_xyz[3 * ib2 + 2] };
    }

    __shared__ float4 tile[TILE];
    const int jbase = by * TILE;
    if (tid < TILE) {
        const int j = jbase + tid;
        const float px = new_xyz[3 * j + 0];
        const float py = new_xyz[3 * j + 1];
        const float pz = new_xyz[3 * j + 2];
        const float sqj = px * px + py * py + pz * pz;
        const bool ins = gt_sdf[j] < 1e-8f;
        tile[tid] = make_float4(px, py, pz, ins ? sqj : 3e30f);
    }
    __syncthreads();

    float bd[ACCS];
    int bk[ACCS];
    #pragma unroll
    for (int a = 0; a < ACCS; ++a) { bd[a] = 3.0e38f; bk[a] = 0; }

    // dirty iff the block's j-tile intersects its i-range (wave-uniform branch)
    const bool dirty = (jbase < ibase + IB) && (jbase + TILE > ibase);
    if (dirty)
        nn_inner<true>(tile, jbase, ibase_t, wx, wy, wz, bd, bk);
    else
        nn_inner<false>(tile, jbase, ibase_t, wx, wy, wz, bd, bk);

    #pragma unroll
    for (int a = 0; a < ACCS; ++a) {
        unsigned kb = __float_as_uint(bd[a]);
        kb = ((int)kb < 0) ? ~kb : (kb | 0x80000000u);
        packed[(size_t)by * N + (ibase_t + a * 256)] =
            ((ull)kb << 32) | (ull)(unsigned)(jbase + bk[a]);
    }
}

// ---------------------------------------------------------------------------
// Kernel B: per-i u64-min over the 128 split slots, strain quadratic form,
// block partials (no atomics, no memset).
// ---------------------------------------------------------------------------
__global__ __launch_bounds__(256) void loss_kernel(
    const float* __restrict__ new_xyz,
    const float* __restrict__ xyz,
    const float* __restrict__ gt_sdf,
    const ull* __restrict__ packed,
    double* __restrict__ partial_sum,
    unsigned int* __restrict__ partial_cnt,
    CMat C)
{
    const int tid = threadIdx.x;
    const int i = blockIdx.x * 256 + tid;

    ull best = ~0ull;
    #pragma unroll 8
    for (int s = 0; s < NBY; ++s) {
        const ull p = packed[(size_t)s * N + i];
        best = (p < best) ? p : best;
    }

    const unsigned kb = (unsigned)(best >> 32);
    const unsigned bits = (kb & 0x80000000u) ? (kb ^ 0x80000000u) : ~kb;
    const float key = __uint_as_float(bits);   // = min_j (sqj_masked - 2*dot)
    const int nn = (int)(unsigned)(best & 0xffffffffu);

    const float wix = new_xyz[3 * i + 0];
    const float wiy = new_xyz[3 * i + 1];
    const float wiz = new_xyz[3 * i + 2];
    const float sqi = wix * wix + wiy * wiy + wiz * wiz;

    const float d2 = sqi + key;
    const float nnd = sqrtf(fmaxf(d2, 0.0f));
    const bool inside = gt_sdf[i] < 1e-8f;
    const bool valid = inside && (nnd > 1e-8f);

    float q = 0.0f;
    if (valid) {
        const float xix = xyz[3 * i + 0], xiy = xyz[3 * i + 1], xiz = xyz[3 * i + 2];
        const float wnx = new_xyz[3 * nn + 0], wny = new_xyz[3 * nn + 1], wnz = new_xyz[3 * nn + 2];
        const float xnx = xyz[3 * nn + 0],     xny = xyz[3 * nn + 1],     xnz = xyz[3 * nn + 2];

        const float du = (wnx - xnx) - (wix - xix);
        const float dv = (wny - xny) - (wiy - xiy);
        const float dw = (wnz - xnz) - (wiz - xiz);
        const float dx = wnx - wix + 1e-8f;
        const float dy = wny - wiy + 1e-8f;
        const float dz = wnz - wiz + 1e-8f;

        float et[6];
        et[0] = du / dx;
        et[1] = dv / dy;
        et[2] = dw / dz;
        et[3] = (du / dy + dv / dx) * 0.5f;
        et[4] = (du / dz + dw / dx) * 0.5f;
        et[5] = (dw / dy + dv / dz) * 0.5f;

        #pragma unroll
        for (int a = 0; a < 6; ++a) {
            float s = 0.0f;
            #pragma unroll
            for (int b = 0; b < 6; ++b) s += C.c[a][b] * et[b];
            q += et[a] * s;
        }
    }

    double q2 = (double)q * (double)q;
    #pragma unroll
    for (int off = 32; off > 0; off >>= 1)
        q2 += __shfl_down(q2, off, 64);
    const ull vm = __ballot(valid);
    const int lane = tid & 63;
    const int wid = tid >> 6;

    __shared__ double wsum[4];
    __shared__ unsigned wcnt[4];
    if (lane == 0) { wsum[wid] = q2; wcnt[wid] = (unsigned)__popcll(vm); }
    __syncthreads();
    if (tid == 0) {
        double s = wsum[0] + wsum[1] + wsum[2] + wsum[3];
        unsigned c = wcnt[0] + wcnt[1] + wcnt[2] + wcnt[3];
        partial_sum[blockIdx.x] = s;
        partial_cnt[blockIdx.x] = c;
    }
}

// ---------------------------------------------------------------------------
// Kernel C: finalize — sum 48 partials, out = sqrt(sum q^2) / n_valid
// ---------------------------------------------------------------------------
#define NPART (N / 256)   // 48

__global__ void final_kernel(const double* __restrict__ partial_sum,
                             const unsigned int* __restrict__ partial_cnt,
                             float* __restrict__ out)
{
    const int lane = threadIdx.x;   // 64 threads
    double s = (lane < NPART) ? partial_sum[lane] : 0.0;
    double c = (lane < NPART) ? (double)partial_cnt[lane] : 0.0;
    #pragma unroll
    for (int off = 32; off > 0; off >>= 1) {
        s += __shfl_down(s, off, 64);
        c += __shfl_down(c, off, 64);
    }
    if (lane == 0) out[0] = (float)(sqrt(s) / c);
}

// ---------------- Host: build C = inv(Ci) -----------------------------------
static void build_cmat(CMat* M)
{
    const double VP = 0.4, EP = 0.21;
    double A[6][12];
    memset(A, 0, sizeof(A));
    double Ci[6][6];
    memset(Ci, 0, sizeof(Ci));
    Ci[0][0] = 1.0 / EP; Ci[0][1] = -VP / EP; Ci[0][2] = -VP / EP;
    Ci[1][0] = -VP / EP; Ci[1][1] = 1.0 / EP; Ci[1][2] = -VP / EP;
    Ci[2][0] = -VP;      Ci[2][1] = -VP;      Ci[2][2] = 1.0 / EP;
    Ci[3][3] = 2.0 * (1.0 + VP) / EP;
    Ci[4][4] = Ci[3][3];
    Ci[5][5] = Ci[3][3];

    for (int i = 0; i < 6; ++i) {
        for (int j = 0; j < 6; ++j) A[i][j] = Ci[i][j];
        A[i][6 + i] = 1.0;
    }
    for (int col = 0; col < 6; ++col) {
        int piv = col;
        for (int r = col + 1; r < 6; ++r)
            if (fabs(A[r][col]) > fabs(A[piv][col])) piv = r;
        if (piv != col)
            for (int c = 0; c < 12; ++c) { double t = A[col][c]; A[col][c] = A[piv][c]; A[piv][c] = t; }
        const double d = A[col][col];
        for (int c = 0; c < 12; ++c) A[col][c] /= d;
        for (int r = 0; r < 6; ++r) {
            if (r == col) continue;
            const double f = A[r][col];
            if (f == 0.0) continue;
            for (int c = 0; c < 12; ++c) A[r][c] -= f * A[col][c];
        }
    }
    for (int i = 0; i < 6; ++i)
        for (int j = 0; j < 6; ++j)
            M->c[i][j] = (float)A[i][6 + j];
}

extern "C" void kernel_launch(void* const* d_in, const int* in_sizes, int n_in,
                              void* d_out, int out_size, void* d_ws, size_t ws_size,
                              hipStream_t stream)
{
    const float* new_xyz = (const float*)d_in[0];
    const float* xyz     = (const float*)d_in[1];
    const float* gt_sdf  = (const float*)d_in[2];
    float* out = (float*)d_out;

    // workspace layout (fully written before read — no memset needed):
    //   [0, NBY*N*8)  : packed u64 per (split, i)   (12.6 MB)
    //   then NPART doubles (partial_sum), NPART uints (partial_cnt)
    const size_t packed_bytes = (size_t)NBY * N * sizeof(ull);
    ull* packed = (ull*)d_ws;
    double* partial_sum = (double*)((char*)d_ws + packed_bytes);
    unsigned int* partial_cnt =
        (unsigned int*)((char*)d_ws + packed_bytes + NPART * sizeof(double));

    CMat C;
    build_cmat(&C);

    nn_kernel<<<dim3(NBX, NBY), 256, 0, stream>>>(new_xyz, gt_sdf, packed);
    loss_kernel<<<N / 256, 256, 0, stream>>>(new_xyz, xyz, gt_sdf, packed,
                                             partial_sum, partial_cnt, C);
    final_kernel<<<1, 64, 0, stream>>>(partial_sum, partial_cnt, out);
}

// Round 4
// 93.908 us; speedup vs baseline: 1.1116x; 1.1116x over previous
//
#include <hip/hip_runtime.h>
#include <math.h>
#include <string.h>

#define N 12288
#define TILE 96           // j-points per block (one LDS tile)
#define ACCS 8            // i-points per thread
#define IB (256 * ACCS)   // 2048 i-points per block
#define NBX (N / IB)      // 6
#define NBY (N / TILE)    // 128  -> grid 768 = exactly 3 blocks/CU

typedef unsigned long long ull;

struct CMat { float c[6][6]; };

// ---------------------------------------------------------------------------
// Kernel A: brute-force masked NN. Block (bx,by) owns i in [bx*2048, +2048)
// (8 per thread, scalar chains) and j in [by*96, +96) in LDS.
// Tile holds (-2x, -2y, -2z, sqj_masked) so key d' = sqj - 2*dot is 3 fma.
// (sqi is added back in the reducer.) Writes (monotone-key<<32 | j) to a
// private slot packed[by*N + i] — no atomics, no memset.
// ---------------------------------------------------------------------------
template<bool CAREFUL>
__device__ __forceinline__ void nn_inner(
    const float4* __restrict__ tile,
    const float* wx, const float* wy, const float* wz,
    const int* kx,
    float* bd, int* bk)
{
    #pragma unroll 8
    for (int k = 0; k < TILE; ++k) {
        const float4 b = tile[k];
        #pragma unroll
        for (int a = 0; a < ACCS; ++a) {
            float d = fmaf(wz[a], b.z, b.w);
            d = fmaf(wy[a], b.y, d);
            d = fmaf(wx[a], b.x, d);
            bool ok = d < bd[a];
            if (CAREFUL) ok = ok && (k != kx[a]);
            if (ok) { bd[a] = d; bk[a] = k; }
        }
    }
}

__global__ __launch_bounds__(256, 3) void nn_kernel(
    const float* __restrict__ new_xyz,
    const float* __restrict__ gt_sdf,
    ull* __restrict__ packed)
{
    const int tid = threadIdx.x;
    const int bx = blockIdx.x;
    const int by = blockIdx.y;

    const int ibase = bx * IB;
    const int ibase_t = ibase + tid;   // i of acc a is ibase_t + a*256
    const int jbase = by * TILE;

    float wx[ACCS], wy[ACCS], wz[ACCS];
    int kx[ACCS];
    #pragma unroll
    for (int a = 0; a < ACCS; ++a) {
        const int ia = ibase_t + a * 256;
        wx[a] = new_xyz[3 * ia + 0];
        wy[a] = new_xyz[3 * ia + 1];
        wz[a] = new_xyz[3 * ia + 2];
        kx[a] = ia - jbase;            // colliding k (self), if in [0,TILE)
    }

    __shared__ float4 tile[TILE];
    if (tid < TILE) {
        const int j = jbase + tid;
        const float px = new_xyz[3 * j + 0];
        const float py = new_xyz[3 * j + 1];
        const float pz = new_xyz[3 * j + 2];
        const float sqj = px * px + py * py + pz * pz;
        const bool ins = gt_sdf[j] < 1e-8f;
        tile[tid] = make_float4(-2.0f * px, -2.0f * py, -2.0f * pz,
                                ins ? sqj : 3e30f);
    }
    __syncthreads();

    float bd[ACCS];
    int bk[ACCS];
    #pragma unroll
    for (int a = 0; a < ACCS; ++a) { bd[a] = 3.0e38f; bk[a] = 0; }

    // dirty iff this block's j-tile intersects its i-range (uniform branch)
    const bool dirty = (jbase < ibase + IB) && (jbase + TILE > ibase);
    if (dirty)
        nn_inner<true>(tile, wx, wy, wz, kx, bd, bk);
    else
        nn_inner<false>(tile, wx, wy, wz, kx, bd, bk);

    #pragma unroll
    for (int a = 0; a < ACCS; ++a) {
        unsigned kb = __float_as_uint(bd[a]);
        kb = ((int)kb < 0) ? ~kb : (kb | 0x80000000u);
        packed[(size_t)by * N + (ibase_t + a * 256)] =
            ((ull)kb << 32) | (ull)(unsigned)(jbase + bk[a]);
    }
}

// ---------------------------------------------------------------------------
// Kernel B: per-i u64-min over the 128 split slots (4 threads per point,
// 32 slots each, shuffle-min), strain quadratic form, block partials.
// Block covers 64 points; grid = N/64 = 192 blocks.
// ---------------------------------------------------------------------------
__global__ __launch_bounds__(256) void loss_kernel(
    const float* __restrict__ new_xyz,
    const float* __restrict__ xyz,
    const float* __restrict__ gt_sdf,
    const ull* __restrict__ packed,
    double* __restrict__ partial_sum,
    unsigned int* __restrict__ partial_cnt,
    CMat C)
{
    const int tid = threadIdx.x;
    const int il = tid >> 2;          // 0..63 : point within block
    const int chunk = tid & 3;        // 0..3  : split-chunk
    const int i = blockIdx.x * 64 + il;

    ull best = ~0ull;
    #pragma unroll 8
    for (int s = 0; s < NBY / 4; ++s) {
        const ull p = packed[(size_t)(chunk * (NBY / 4) + s) * N + i];
        best = (p < best) ? p : best;
    }
    {   // min over the 4 chunk-threads (adjacent lanes)
        ull o = __shfl_xor(best, 1, 64);
        best = (o < best) ? o : best;
        o = __shfl_xor(best, 2, 64);
        best = (o < best) ? o : best;
    }

    __shared__ ull bmin[64];
    if ((tid & 3) == 0) bmin[il] = best;
    __syncthreads();

    if (tid < 64) {
        const int ii = blockIdx.x * 64 + tid;
        const ull b = bmin[tid];
        const unsigned kb = (unsigned)(b >> 32);
        const unsigned bits = (kb & 0x80000000u) ? (kb ^ 0x80000000u) : ~kb;
        const float key = __uint_as_float(bits);   // min_j (sqj_masked - 2*dot)
        const int nn = (int)(unsigned)(b & 0xffffffffu);

        const float wix = new_xyz[3 * ii + 0];
        const float wiy = new_xyz[3 * ii + 1];
        const float wiz = new_xyz[3 * ii + 2];
        const float sqi = wix * wix + wiy * wiy + wiz * wiz;

        const float d2 = sqi + key;
        const float nnd = sqrtf(fmaxf(d2, 0.0f));
        const bool inside = gt_sdf[ii] < 1e-8f;
        const bool valid = inside && (nnd > 1e-8f);

        float q = 0.0f;
        if (valid) {
            const float xix = xyz[3 * ii + 0], xiy = xyz[3 * ii + 1], xiz = xyz[3 * ii + 2];
            const float wnx = new_xyz[3 * nn + 0], wny = new_xyz[3 * nn + 1], wnz = new_xyz[3 * nn + 2];
            const float xnx = xyz[3 * nn + 0],     xny = xyz[3 * nn + 1],     xnz = xyz[3 * nn + 2];

            const float du = (wnx - xnx) - (wix - xix);
            const float dv = (wny - xny) - (wiy - xiy);
            const float dw = (wnz - xnz) - (wiz - xiz);
            const float dx = wnx - wix + 1e-8f;
            const float dy = wny - wiy + 1e-8f;
            const float dz = wnz - wiz + 1e-8f;

            float et[6];
            et[0] = du / dx;
            et[1] = dv / dy;
            et[2] = dw / dz;
            et[3] = (du / dy + dv / dx) * 0.5f;
            et[4] = (du / dz + dw / dx) * 0.5f;
            et[5] = (dw / dy + dv / dz) * 0.5f;

            #pragma unroll
            for (int a = 0; a < 6; ++a) {
                float s = 0.0f;
                #pragma unroll
                for (int b2 = 0; b2 < 6; ++b2) s += C.c[a][b2] * et[b2];
                q += et[a] * s;
            }
        }

        // single-wave reduction (threads 0..63 are wave 0)
        double q2 = (double)q * (double)q;
        #pragma unroll
        for (int off = 32; off > 0; off >>= 1)
            q2 += __shfl_down(q2, off, 64);
        const ull vm = __ballot(valid);
        if (tid == 0) {
            partial_sum[blockIdx.x] = q2;
            partial_cnt[blockIdx.x] = (unsigned)__popcll(vm);
        }
    }
}

// ---------------------------------------------------------------------------
// Kernel C: finalize — sum 192 partials, out = sqrt(sum q^2) / n_valid
// ---------------------------------------------------------------------------
#define NPART (N / 64)   // 192

__global__ void final_kernel(const double* __restrict__ partial_sum,
                             const unsigned int* __restrict__ partial_cnt,
                             float* __restrict__ out)
{
    const int lane = threadIdx.x;   // 64 threads
    double s = 0.0, c = 0.0;
    #pragma unroll
    for (int k = 0; k < NPART / 64; ++k) {
        s += partial_sum[lane + 64 * k];
        c += (double)partial_cnt[lane + 64 * k];
    }
    #pragma unroll
    for (int off = 32; off > 0; off >>= 1) {
        s += __shfl_down(s, off, 64);
        c += __shfl_down(c, off, 64);
    }
    if (lane == 0) out[0] = (float)(sqrt(s) / c);
}

// ---------------- Host: build C = inv(Ci) -----------------------------------
static void build_cmat(CMat* M)
{
    const double VP = 0.4, EP = 0.21;
    double A[6][12];
    memset(A, 0, sizeof(A));
    double Ci[6][6];
    memset(Ci, 0, sizeof(Ci));
    Ci[0][0] = 1.0 / EP; Ci[0][1] = -VP / EP; Ci[0][2] = -VP / EP;
    Ci[1][0] = -VP / EP; Ci[1][1] = 1.0 / EP; Ci[1][2] = -VP / EP;
    Ci[2][0] = -VP;      Ci[2][1] = -VP;      Ci[2][2] = 1.0 / EP;
    Ci[3][3] = 2.0 * (1.0 + VP) / EP;
    Ci[4][4] = Ci[3][3];
    Ci[5][5] = Ci[3][3];

    for (int i = 0; i < 6; ++i) {
        for (int j = 0; j < 6; ++j) A[i][j] = Ci[i][j];
        A[i][6 + i] = 1.0;
    }
    for (int col = 0; col < 6; ++col) {
        int piv = col;
        for (int r = col + 1; r < 6; ++r)
            if (fabs(A[r][col]) > fabs(A[piv][col])) piv = r;
        if (piv != col)
            for (int c = 0; c < 12; ++c) { double t = A[col][c]; A[col][c] = A[piv][c]; A[piv][c] = t; }
        const double d = A[col][col];
        for (int c = 0; c < 12; ++c) A[col][c] /= d;
        for (int r = 0; r < 6; ++r) {
            if (r == col) continue;
            const double f = A[r][col];
            if (f == 0.0) continue;
            for (int c = 0; c < 12; ++c) A[r][c] -= f * A[col][c];
        }
    }
    for (int i = 0; i < 6; ++i)
        for (int j = 0; j < 6; ++j)
            M->c[i][j] = (float)A[i][6 + j];
}

extern "C" void kernel_launch(void* const* d_in, const int* in_sizes, int n_in,
                              void* d_out, int out_size, void* d_ws, size_t ws_size,
                              hipStream_t stream)
{
    const float* new_xyz = (const float*)d_in[0];
    const float* xyz     = (const float*)d_in[1];
    const float* gt_sdf  = (const float*)d_in[2];
    float* out = (float*)d_out;

    // workspace layout (fully written before read — no memset needed):
    //   [0, NBY*N*8)  : packed u64 per (split, i)   (12.6 MB)
    //   then NPART doubles (partial_sum), NPART uints (partial_cnt)
    const size_t packed_bytes = (size_t)NBY * N * sizeof(ull);
    ull* packed = (ull*)d_ws;
    double* partial_sum = (double*)((char*)d_ws + packed_bytes);
    unsigned int* partial_cnt =
        (unsigned int*)((char*)d_ws + packed_bytes + NPART * sizeof(double));

    CMat C;
    build_cmat(&C);

    nn_kernel<<<dim3(NBX, NBY), 256, 0, stream>>>(new_xyz, gt_sdf, packed);
    loss_kernel<<<N / 64, 256, 0, stream>>>(new_xyz, xyz, gt_sdf, packed,
                                            partial_sum, partial_cnt, C);
    final_kernel<<<1, 64, 0, stream>>>(partial_sum, partial_cnt, out);
}